// Round 9
// baseline (599.719 us; speedup 1.0000x reference)
//
#include <hip/hip_runtime.h>
#include <math.h>

// (S,N,B,T,D) = (8,8,2,2048,1024)
// Grid 8192 = (xcd 8) x (k 1024); XCD owns contiguous btp range; k%4 = s-pair.
// Block: 256 thr = 4 waves; waves {0,1} -> bt_a, {2,3} -> bt_b; thread owns
// 8 d-elements (float4 at d0 and d0+256). V is consumed streaming in the dot
// loop and RE-LOADED from XCD-local L2 in phase E (no 64-reg V residency).
#define TPB 256

template <int CTRL>
__device__ __forceinline__ float dpp_add(float x) {
    int yi = __builtin_amdgcn_update_dpp(0, __float_as_int(x), CTRL, 0xF, 0xF, true);
    return x + __int_as_float(yi);
}

// 64-lane sum, pure VALU; TOTAL lands in lane 63.
__device__ __forceinline__ float wave_sum63(float x) {
    x = dpp_add<0xB1>(x);    // xor 1
    x = dpp_add<0x4E>(x);    // xor 2
    x = dpp_add<0x141>(x);   // row_half_mirror
    x = dpp_add<0x140>(x);   // row_mirror -> 16-lane row sums
    x = dpp_add<0x142>(x);   // row_bcast15
    x = dpp_add<0x143>(x);   // row_bcast31 -> lane63 = total
    return x;
}

__device__ __forceinline__ float dot4(const float4 a, const float4 b) {
    return a.x*b.x + a.y*b.y + a.z*b.z + a.w*b.w;
}

__global__ __launch_bounds__(TPB, 6) void two_phase_attn_kernel(
    const float* __restrict__ q,    // [8][1024]
    const float* __restrict__ V,    // block_reps  [8][2][2048][1024]
    const float* __restrict__ P,    // partial_sums[8][2][2048][1024]
    const float* __restrict__ wgt,  // [1024]
    float* __restrict__ out)        // merged_out | merged_max | merged_lse
{
    constexpr int    N   = 8;
    constexpr int    BT  = 4096;
    constexpr int    D   = 1024;
    constexpr size_t ROW = (size_t)BT * D;
    constexpr size_t OUT_MM  = (size_t)8 * ROW;
    constexpr size_t OUT_LSE = OUT_MM + (size_t)BT * 8;
    constexpr float  SCALE = 0.03125f;
    constexpr float  EPS   = 1e-6f;

    __shared__ float red[4][28];    // per-wave reduced partials (448 B)

    const int tid  = threadIdx.x;
    const int w    = tid >> 6;
    const int lane = tid & 63;

    // XCD-aware decomposition (dispatch round-robins blockIdx % 8 -> XCD)
    const int b   = blockIdx.x;
    const int xcd = b & 7;
    const int k   = b >> 3;
    const int btp = xcd * 256 + (k >> 2);
    const int sp  = k & 3;
    const int s0  = 2 * sp, s1 = s0 + 1;

    const int bt  = 2 * btp + (w >> 1);          // waves 0,1 -> bt_a; 2,3 -> bt_b
    const int d0  = (w & 1) * 512 + lane * 4;    // owns d0 and d0+256
    const size_t btD = (size_t)bt * D;

    const float* Vb = V + btD + d0;              // + n*ROW per V row
    const float* P0 = P + (size_t)s0 * ROW + btD + d0;
    const float* P1 = P + (size_t)s1 * ROW + btD + d0;

    // ---- P loads early (4 independent float4; consumed almost immediately) ----
    float4 p0[2], p1[2];
    p0[0] = *(const float4*)(P0);        p0[1] = *(const float4*)(P0 + 256);
    p1[0] = *(const float4*)(P1);        p1[1] = *(const float4*)(P1 + 256);

    // ---- q*w (L1/L2-hot) ----
    float4 qw0[2], qw1[2];
    #pragma unroll
    for (int c = 0; c < 2; ++c) {
        const int d = d0 + c * 256;
        const float4 a0 = *(const float4*)(q + s0 * D + d);
        const float4 a1 = *(const float4*)(q + s1 * D + d);
        const float4 wv = *(const float4*)(wgt + d);
        qw0[c] = make_float4(a0.x*wv.x, a0.y*wv.y, a0.z*wv.z, a0.w*wv.w);
        qw1[c] = make_float4(a1.x*wv.x, a1.y*wv.y, a1.z*wv.z, a1.w*wv.w);
    }

    // r[0..7]=dot(qw0,V[n]) r[8..15]=dot(qw1,V[n]) r[16..23]=vsq[n]
    // r[24]=ssq(P0) r[25]=ssq(P1) r[26]=dot(qw0,P0) r[27]=dot(qw1,P1)
    float r[28];

    // ---- P-dots first (P already arriving; frees nothing but starts exchange) ----
    r[24] = dot4(p0[0], p0[0]) + dot4(p0[1], p0[1]);
    r[25] = dot4(p1[0], p1[0]) + dot4(p1[1], p1[1]);
    r[26] = dot4(qw0[0], p0[0]) + dot4(qw0[1], p0[1]);
    r[27] = dot4(qw1[0], p1[0]) + dot4(qw1[1], p1[1]);

    // ---- V dot loop: streaming, V not kept live ----
    #pragma unroll
    for (int n = 0; n < N; ++n) {
        const float4 v0 = *(const float4*)(Vb + (size_t)n * ROW);
        const float4 v1 = *(const float4*)(Vb + (size_t)n * ROW + 256);
        r[n]      = dot4(qw0[0], v0) + dot4(qw0[1], v1);
        r[8 + n]  = dot4(qw1[0], v0) + dot4(qw1[1], v1);
        r[16 + n] = dot4(v0, v0)     + dot4(v1, v1);
    }

    // ---- Wave reduce (28 independent DPP chains; totals in lane 63) ----
    #pragma unroll
    for (int i = 0; i < 28; ++i) r[i] = wave_sum63(r[i]);

    // ---- Cross-wave exchange (static indices only) ----
    if (lane == 63) {
        *(float4*)(&red[w][0])  = make_float4(r[0],  r[1],  r[2],  r[3]);
        *(float4*)(&red[w][4])  = make_float4(r[4],  r[5],  r[6],  r[7]);
        *(float4*)(&red[w][8])  = make_float4(r[8],  r[9],  r[10], r[11]);
        *(float4*)(&red[w][12]) = make_float4(r[12], r[13], r[14], r[15]);
        *(float4*)(&red[w][16]) = make_float4(r[16], r[17], r[18], r[19]);
        *(float4*)(&red[w][20]) = make_float4(r[20], r[21], r[22], r[23]);
        *(float4*)(&red[w][24]) = make_float4(r[24], r[25], r[26], r[27]);
    }
    __syncthreads();

    const int g = (w >> 1) * 2;              // first wave of this bt-group
    float rv = 0.f;
    if (lane < 28) rv = red[g][lane] + red[g + 1][lane];

    float rs[28];
    #pragma unroll
    for (int i = 0; i < 28; ++i)
        rs[i] = __int_as_float(__builtin_amdgcn_readlane(__float_as_int(rv), i));

    // ---- Phase 1 softmax over n (wave-uniform scalars) ----
    float e0[N], e1[N];
    float m0 = -1e30f, m1 = -1e30f;
    #pragma unroll
    for (int n = 0; n < N; ++n) {
        const float rinv = rsqrtf(rs[16 + n] * (1.0f/1024.0f) + EPS);
        e0[n] = rs[n]     * rinv * SCALE;  m0 = fmaxf(m0, e0[n]);
        e1[n] = rs[8 + n] * rinv * SCALE;  m1 = fmaxf(m1, e1[n]);
    }
    float es0 = 0.f, es1 = 0.f;
    #pragma unroll
    for (int n = 0; n < N; ++n) {
        e0[n] = __expf(e0[n] - m0);  es0 += e0[n];
        e1[n] = __expf(e1[n] - m1);  es1 += e1[n];
    }

    // ---- Phase 2 merge scalars ----
    const float im0 = rs[26] * rsqrtf(rs[24] * (1.0f/1024.0f) + EPS) * SCALE;
    const float im1 = rs[27] * rsqrtf(rs[25] * (1.0f/1024.0f) + EPS) * SCALE;
    const float mm0 = fmaxf(m0, im0),    mm1 = fmaxf(m1, im1);
    const float wi0 = __expf(m0 - mm0),  wi1 = __expf(m1 - mm1);
    const float wa0 = __expf(im0 - mm0), wa1 = __expf(im1 - mm1);
    const float lse0 = __logf(wi0 * es0 + wa0) + mm0;   // exp(inter_lse-inter_max)==es
    const float lse1 = __logf(wi1 * es1 + wa1) + mm1;
    const float nrm0 = wi0 + wa0,         nrm1 = wi1 + wa1;
    const float cA0 = wi0 / (es0 * nrm0), cA1 = wi1 / (es1 * nrm1);
    const float cp0 = wa0 / nrm0,         cp1 = wa1 / nrm1;

    // ---- Phase E: re-load V from XCD-local L2, accumulate, merge, store ----
    float4 A00 = make_float4(0.f,0.f,0.f,0.f), A01 = make_float4(0.f,0.f,0.f,0.f);
    float4 A10 = make_float4(0.f,0.f,0.f,0.f), A11 = make_float4(0.f,0.f,0.f,0.f);
    #pragma unroll
    for (int n = 0; n < N; ++n) {
        const float4 v0 = *(const float4*)(Vb + (size_t)n * ROW);
        const float4 v1 = *(const float4*)(Vb + (size_t)n * ROW + 256);
        const float c0 = e0[n], c1 = e1[n];
        A00.x += c0*v0.x; A00.y += c0*v0.y; A00.z += c0*v0.z; A00.w += c0*v0.w;
        A01.x += c0*v1.x; A01.y += c0*v1.y; A01.z += c0*v1.z; A01.w += c0*v1.w;
        A10.x += c1*v0.x; A10.y += c1*v0.y; A10.z += c1*v0.z; A10.w += c1*v0.w;
        A11.x += c1*v1.x; A11.y += c1*v1.y; A11.z += c1*v1.z; A11.w += c1*v1.w;
    }
    float4 o;
    o.x = cA0*A00.x + cp0*p0[0].x;  o.y = cA0*A00.y + cp0*p0[0].y;
    o.z = cA0*A00.z + cp0*p0[0].z;  o.w = cA0*A00.w + cp0*p0[0].w;
    *(float4*)(out + (size_t)s0 * ROW + btD + d0) = o;
    o.x = cA0*A01.x + cp0*p0[1].x;  o.y = cA0*A01.y + cp0*p0[1].y;
    o.z = cA0*A01.z + cp0*p0[1].z;  o.w = cA0*A01.w + cp0*p0[1].w;
    *(float4*)(out + (size_t)s0 * ROW + btD + d0 + 256) = o;
    o.x = cA1*A10.x + cp1*p1[0].x;  o.y = cA1*A10.y + cp1*p1[0].y;
    o.z = cA1*A10.z + cp1*p1[0].z;  o.w = cA1*A10.w + cp1*p1[0].w;
    *(float4*)(out + (size_t)s1 * ROW + btD + d0) = o;
    o.x = cA1*A11.x + cp1*p1[1].x;  o.y = cA1*A11.y + cp1*p1[1].y;
    o.z = cA1*A11.z + cp1*p1[1].z;  o.w = cA1*A11.w + cp1*p1[1].w;
    *(float4*)(out + (size_t)s1 * ROW + btD + d0 + 256) = o;

    if ((w & 1) == 0 && lane == 0) {         // one writer per (bt, s-pair)
        out[OUT_MM  + (size_t)s0 * BT + bt] = mm0;
        out[OUT_MM  + (size_t)s1 * BT + bt] = mm1;
        out[OUT_LSE + (size_t)s0 * BT + bt] = lse0;
        out[OUT_LSE + (size_t)s1 * BT + bt] = lse1;
    }
}

extern "C" void kernel_launch(void* const* d_in, const int* in_sizes, int n_in,
                              void* d_out, int out_size, void* d_ws, size_t ws_size,
                              hipStream_t stream) {
    const float* q   = (const float*)d_in[0];   // pseudo_queries [8,1024]
    const float* V   = (const float*)d_in[1];   // block_reps     [8,2,2048,1024]
    const float* P   = (const float*)d_in[2];   // partial_sums   [8,2,2048,1024]
    const float* wgt = (const float*)d_in[3];   // norm_weight    [1024]
    float* o = (float*)d_out;

    two_phase_attn_kernel<<<8192, TPB, 0, stream>>>(q, V, P, wgt, o);
}

// Round 10
// 309.670 us; speedup vs baseline: 1.9366x; 1.9366x over previous
//
#include <hip/hip_runtime.h>
#include <math.h>

// (S,N,B,T,D) = (8,8,2,2048,1024)
// Grid 8192 = (xcd 8) x (k 1024); XCD owns contiguous btp range; k%4 = s-pair.
// Block: 256 thr = 4 waves; waves {0,1} -> bt_a, {2,3} -> bt_b; thread owns
// 8 d-elements (float4 chunks at d0, d0+256). V register-resident through
// phase E. launch_bounds(256,4): VGPR cap 128 -> full 26-load MLP burst,
// same 4-waves/SIMD cap as R7's 68. NO forced occupancy beyond that (R8/R9
// spill lesson).
#define TPB 256

template <int CTRL>
__device__ __forceinline__ float dpp_add(float x) {
    int yi = __builtin_amdgcn_update_dpp(0, __float_as_int(x), CTRL, 0xF, 0xF, true);
    return x + __int_as_float(yi);
}

// 64-lane sum, pure VALU; TOTAL lands in lane 63.
__device__ __forceinline__ float wave_sum63(float x) {
    x = dpp_add<0xB1>(x);    // xor 1
    x = dpp_add<0x4E>(x);    // xor 2
    x = dpp_add<0x141>(x);   // row_half_mirror
    x = dpp_add<0x140>(x);   // row_mirror -> 16-lane row sums
    x = dpp_add<0x142>(x);   // row_bcast15
    x = dpp_add<0x143>(x);   // row_bcast31 -> lane63 = total
    return x;
}

__device__ __forceinline__ float dot4(const float4 a, const float4 b) {
    return a.x*b.x + a.y*b.y + a.z*b.z + a.w*b.w;
}

__global__ __launch_bounds__(TPB, 4) void two_phase_attn_kernel(
    const float* __restrict__ q,    // [8][1024]
    const float* __restrict__ V,    // block_reps  [8][2][2048][1024]
    const float* __restrict__ P,    // partial_sums[8][2][2048][1024]
    const float* __restrict__ wgt,  // [1024]
    float* __restrict__ out)        // merged_out | merged_max | merged_lse
{
    constexpr int    N   = 8;
    constexpr int    BT  = 4096;
    constexpr int    D   = 1024;
    constexpr size_t ROW = (size_t)BT * D;
    constexpr size_t OUT_MM  = (size_t)8 * ROW;
    constexpr size_t OUT_LSE = OUT_MM + (size_t)BT * 8;
    constexpr float  SCALE = 0.03125f;
    constexpr float  EPS   = 1e-6f;

    __shared__ float red[4][28];    // per-wave reduced partials (448 B)

    const int tid  = threadIdx.x;
    const int w    = tid >> 6;
    const int lane = tid & 63;

    // XCD-aware decomposition (dispatch round-robins blockIdx % 8 -> XCD)
    const int b   = blockIdx.x;
    const int xcd = b & 7;
    const int k   = b >> 3;
    const int btp = xcd * 256 + (k >> 2);
    const int sp  = k & 3;
    const int s0  = 2 * sp, s1 = s0 + 1;

    const int bt  = 2 * btp + (w >> 1);          // waves 0,1 -> bt_a; 2,3 -> bt_b
    const int d0  = (w & 1) * 512 + lane * 4;    // owns d0 and d0+256
    const size_t btD = (size_t)bt * D;

    // ---- All global loads issued up front (26 independent float4/thread) ----
    float4 v[N][2];
    #pragma unroll
    for (int n = 0; n < N; ++n) {
        v[n][0] = *(const float4*)(V + (size_t)n * ROW + btD + d0);
        v[n][1] = *(const float4*)(V + (size_t)n * ROW + btD + d0 + 256);
    }
    float4 p0[2], p1[2];
    p0[0] = *(const float4*)(P + (size_t)s0 * ROW + btD + d0);
    p0[1] = *(const float4*)(P + (size_t)s0 * ROW + btD + d0 + 256);
    p1[0] = *(const float4*)(P + (size_t)s1 * ROW + btD + d0);
    p1[1] = *(const float4*)(P + (size_t)s1 * ROW + btD + d0 + 256);

    float4 qw0[2], qw1[2];
    #pragma unroll
    for (int c = 0; c < 2; ++c) {
        const int d = d0 + c * 256;
        const float4 a0 = *(const float4*)(q + s0 * D + d);
        const float4 a1 = *(const float4*)(q + s1 * D + d);
        const float4 wv = *(const float4*)(wgt + d);
        qw0[c] = make_float4(a0.x*wv.x, a0.y*wv.y, a0.z*wv.z, a0.w*wv.w);
        qw1[c] = make_float4(a1.x*wv.x, a1.y*wv.y, a1.z*wv.z, a1.w*wv.w);
    }

    // ---- Per-thread partials (28 scalars over the thread's 8 floats) ----
    // r[0..7]=dot(qw0,V[n]) r[8..15]=dot(qw1,V[n]) r[16..23]=vsq[n]
    // r[24]=ssq(P0) r[25]=ssq(P1) r[26]=dot(qw0,P0) r[27]=dot(qw1,P1)
    float r[28];
    #pragma unroll
    for (int n = 0; n < N; ++n) {
        r[n]      = dot4(qw0[0], v[n][0]) + dot4(qw0[1], v[n][1]);
        r[8 + n]  = dot4(qw1[0], v[n][0]) + dot4(qw1[1], v[n][1]);
        r[16 + n] = dot4(v[n][0], v[n][0]) + dot4(v[n][1], v[n][1]);
    }
    r[24] = dot4(p0[0], p0[0]) + dot4(p0[1], p0[1]);
    r[25] = dot4(p1[0], p1[0]) + dot4(p1[1], p1[1]);
    r[26] = dot4(qw0[0], p0[0]) + dot4(qw0[1], p0[1]);
    r[27] = dot4(qw1[0], p1[0]) + dot4(qw1[1], p1[1]);

    // ---- Wave reduce (28 independent DPP chains; totals in lane 63) ----
    #pragma unroll
    for (int i = 0; i < 28; ++i) r[i] = wave_sum63(r[i]);

    // ---- Cross-wave exchange (static indices only) ----
    if (lane == 63) {
        *(float4*)(&red[w][0])  = make_float4(r[0],  r[1],  r[2],  r[3]);
        *(float4*)(&red[w][4])  = make_float4(r[4],  r[5],  r[6],  r[7]);
        *(float4*)(&red[w][8])  = make_float4(r[8],  r[9],  r[10], r[11]);
        *(float4*)(&red[w][12]) = make_float4(r[12], r[13], r[14], r[15]);
        *(float4*)(&red[w][16]) = make_float4(r[16], r[17], r[18], r[19]);
        *(float4*)(&red[w][20]) = make_float4(r[20], r[21], r[22], r[23]);
        *(float4*)(&red[w][24]) = make_float4(r[24], r[25], r[26], r[27]);
    }
    __syncthreads();

    const int g = (w >> 1) * 2;              // first wave of this bt-group
    float rv = 0.f;
    if (lane < 28) rv = red[g][lane] + red[g + 1][lane];

    float rs[28];
    #pragma unroll
    for (int i = 0; i < 28; ++i)
        rs[i] = __int_as_float(__builtin_amdgcn_readlane(__float_as_int(rv), i));

    // ---- Phase 1 softmax over n (wave-uniform scalars) ----
    float e0[N], e1[N];
    float m0 = -1e30f, m1 = -1e30f;
    #pragma unroll
    for (int n = 0; n < N; ++n) {
        const float rinv = rsqrtf(rs[16 + n] * (1.0f/1024.0f) + EPS);
        e0[n] = rs[n]     * rinv * SCALE;  m0 = fmaxf(m0, e0[n]);
        e1[n] = rs[8 + n] * rinv * SCALE;  m1 = fmaxf(m1, e1[n]);
    }
    float es0 = 0.f, es1 = 0.f;
    #pragma unroll
    for (int n = 0; n < N; ++n) {
        e0[n] = __expf(e0[n] - m0);  es0 += e0[n];
        e1[n] = __expf(e1[n] - m1);  es1 += e1[n];
    }

    // ---- Phase 2 merge scalars ----
    const float im0 = rs[26] * rsqrtf(rs[24] * (1.0f/1024.0f) + EPS) * SCALE;
    const float im1 = rs[27] * rsqrtf(rs[25] * (1.0f/1024.0f) + EPS) * SCALE;
    const float mm0 = fmaxf(m0, im0),    mm1 = fmaxf(m1, im1);
    const float wi0 = __expf(m0 - mm0),  wi1 = __expf(m1 - mm1);
    const float wa0 = __expf(im0 - mm0), wa1 = __expf(im1 - mm1);
    const float lse0 = __logf(wi0 * es0 + wa0) + mm0;   // exp(inter_lse-inter_max)==es
    const float lse1 = __logf(wi1 * es1 + wa1) + mm1;
    const float nrm0 = wi0 + wa0,         nrm1 = wi1 + wa1;
    const float cA0 = wi0 / (es0 * nrm0), cA1 = wi1 / (es1 * nrm1);
    const float cp0 = wa0 / nrm0,         cp1 = wa1 / nrm1;

    // ---- Phase E: inter_out from register-resident V; merge; store ----
    #pragma unroll
    for (int c = 0; c < 2; ++c) {
        float4 A0 = make_float4(0.f,0.f,0.f,0.f);
        float4 A1 = make_float4(0.f,0.f,0.f,0.f);
        #pragma unroll
        for (int n = 0; n < N; ++n) {
            const float4 vv = v[n][c];
            A0.x += e0[n]*vv.x; A0.y += e0[n]*vv.y; A0.z += e0[n]*vv.z; A0.w += e0[n]*vv.w;
            A1.x += e1[n]*vv.x; A1.y += e1[n]*vv.y; A1.z += e1[n]*vv.z; A1.w += e1[n]*vv.w;
        }
        const float4 pc0 = p0[c], pc1 = p1[c];
        float4 o0, o1;
        o0.x = cA0*A0.x + cp0*pc0.x;  o0.y = cA0*A0.y + cp0*pc0.y;
        o0.z = cA0*A0.z + cp0*pc0.z;  o0.w = cA0*A0.w + cp0*pc0.w;
        o1.x = cA1*A1.x + cp1*pc1.x;  o1.y = cA1*A1.y + cp1*pc1.y;
        o1.z = cA1*A1.z + cp1*pc1.z;  o1.w = cA1*A1.w + cp1*pc1.w;
        *(float4*)(out + (size_t)s0 * ROW + btD + d0 + c*256) = o0;
        *(float4*)(out + (size_t)s1 * ROW + btD + d0 + c*256) = o1;
    }
    if ((w & 1) == 0 && lane == 0) {         // one writer per (bt, s-pair)
        out[OUT_MM  + (size_t)s0 * BT + bt] = mm0;
        out[OUT_MM  + (size_t)s1 * BT + bt] = mm1;
        out[OUT_LSE + (size_t)s0 * BT + bt] = lse0;
        out[OUT_LSE + (size_t)s1 * BT + bt] = lse1;
    }
}

extern "C" void kernel_launch(void* const* d_in, const int* in_sizes, int n_in,
                              void* d_out, int out_size, void* d_ws, size_t ws_size,
                              hipStream_t stream) {
    const float* q   = (const float*)d_in[0];   // pseudo_queries [8,1024]
    const float* V   = (const float*)d_in[1];   // block_reps     [8,2,2048,1024]
    const float* P   = (const float*)d_in[2];   // partial_sums   [8,2,2048,1024]
    const float* wgt = (const float*)d_in[3];   // norm_weight    [1024]
    float* o = (float*)d_out;

    two_phase_attn_kernel<<<8192, TPB, 0, stream>>>(q, V, P, wgt, o);
}

// Round 11
// 123.520 us; speedup vs baseline: 4.8553x; 2.5070x over previous
//
#include <hip/hip_runtime.h>
#include <math.h>

// (S,N,B,T,D) = (8,8,2,2048,1024)
// Grid 8192 = (xcd 8) x (k 1024); XCD owns contiguous btp range; k%4 = s-pair.
// Block: 512 thr = 8 waves. Waves 0-3 -> bt_a (slice w&3), waves 4-7 -> bt_b.
// All 8 V-row chunks register-resident (1 float4 chunk/thread); LDS only for a
// 896 B cross-wave partial exchange. V shared across the 4 sp-blocks via L2.
// NO launch_bounds occupancy arg: R8 (forced 32: spill), R9 (forced 40: spill),
// R10 (bound 4: compiler remat'd loads, +300 MB HBM) all lost to the allocator.
#define TPB 512

template <int CTRL>
__device__ __forceinline__ float dpp_add(float x) {
    int yi = __builtin_amdgcn_update_dpp(0, __float_as_int(x), CTRL, 0xF, 0xF, true);
    return x + __int_as_float(yi);
}

// 64-lane sum, pure VALU; TOTAL lands in lane 63.
__device__ __forceinline__ float wave_sum63(float x) {
    x = dpp_add<0xB1>(x);    // xor 1
    x = dpp_add<0x4E>(x);    // xor 2
    x = dpp_add<0x141>(x);   // row_half_mirror
    x = dpp_add<0x140>(x);   // row_mirror -> 16-lane row sums
    x = dpp_add<0x142>(x);   // row_bcast15
    x = dpp_add<0x143>(x);   // row_bcast31 -> lane63 = total
    return x;
}

__device__ __forceinline__ float dot4(const float4 a, const float4 b) {
    return a.x*b.x + a.y*b.y + a.z*b.z + a.w*b.w;
}

__global__ void two_phase_attn_kernel(
    const float* __restrict__ q,    // [8][1024]
    const float* __restrict__ V,    // block_reps  [8][2][2048][1024]
    const float* __restrict__ P,    // partial_sums[8][2][2048][1024]
    const float* __restrict__ wgt,  // [1024]
    float* __restrict__ out)        // merged_out | merged_max | merged_lse
{
    constexpr int    N   = 8;
    constexpr int    BT  = 4096;
    constexpr int    D   = 1024;
    constexpr size_t ROW = (size_t)BT * D;
    constexpr size_t OUT_MM  = (size_t)8 * ROW;
    constexpr size_t OUT_LSE = OUT_MM + (size_t)BT * 8;
    constexpr float  SCALE = 0.03125f;
    constexpr float  EPS   = 1e-6f;

    __shared__ float red[8][28];    // per-wave reduced partials (896 B)

    const int tid  = threadIdx.x;
    const int w    = tid >> 6;
    const int lane = tid & 63;

    // XCD-aware decomposition (dispatch round-robins blockIdx % 8 -> XCD)
    const int b   = blockIdx.x;
    const int xcd = b & 7;
    const int k   = b >> 3;               // 0..1023 launch order within XCD
    const int btp = xcd * 256 + (k >> 2); // bt-pair, contiguous per XCD
    const int sp  = k & 3;
    const int s0  = 2 * sp, s1 = s0 + 1;

    const int bt  = 2 * btp + (w >> 2);   // waves 0-3 -> bt_a; 4-7 -> bt_b
    const int d0  = (w & 3) * 256 + lane * 4;
    const size_t btD = (size_t)bt * D;

    // ---- All global loads issued up front (13 independent float4/thread) ----
    float4 v[N];
    #pragma unroll
    for (int n = 0; n < N; ++n)
        v[n] = *(const float4*)(V + (size_t)n * ROW + btD + d0);
    const float4 p0 = *(const float4*)(P + (size_t)s0 * ROW + btD + d0);
    const float4 p1 = *(const float4*)(P + (size_t)s1 * ROW + btD + d0);
    const float4 a0 = *(const float4*)(q + s0 * D + d0);
    const float4 a1 = *(const float4*)(q + s1 * D + d0);
    const float4 wv = *(const float4*)(wgt + d0);
    const float4 qw0 = make_float4(a0.x*wv.x, a0.y*wv.y, a0.z*wv.z, a0.w*wv.w);
    const float4 qw1 = make_float4(a1.x*wv.x, a1.y*wv.y, a1.z*wv.z, a1.w*wv.w);

    // ---- Per-thread partials (28 scalars, 4 FMA each) ----
    // r[0..7]=dot(qw0,V[n]) r[8..15]=dot(qw1,V[n]) r[16..23]=vsq[n]
    // r[24]=ssq(P0) r[25]=ssq(P1) r[26]=dot(qw0,P0) r[27]=dot(qw1,P1)
    float r[28];
    #pragma unroll
    for (int n = 0; n < N; ++n) {
        r[n]      = dot4(qw0, v[n]);
        r[8 + n]  = dot4(qw1, v[n]);
        r[16 + n] = dot4(v[n], v[n]);
    }
    r[24] = dot4(p0, p0);
    r[25] = dot4(p1, p1);
    r[26] = dot4(qw0, p0);
    r[27] = dot4(qw1, p1);

    // ---- Wave reduce (28 independent DPP chains) ----
    #pragma unroll
    for (int i = 0; i < 28; ++i) r[i] = wave_sum63(r[i]);

    // ---- Cross-wave exchange: lane63 packs 7 float4 (static idx), barrier,
    //      lanes 0..27 sum their index across the 4 waves of this bt-group ----
    if (lane == 63) {
        *(float4*)(&red[w][0])  = make_float4(r[0],  r[1],  r[2],  r[3]);
        *(float4*)(&red[w][4])  = make_float4(r[4],  r[5],  r[6],  r[7]);
        *(float4*)(&red[w][8])  = make_float4(r[8],  r[9],  r[10], r[11]);
        *(float4*)(&red[w][12]) = make_float4(r[12], r[13], r[14], r[15]);
        *(float4*)(&red[w][16]) = make_float4(r[16], r[17], r[18], r[19]);
        *(float4*)(&red[w][20]) = make_float4(r[20], r[21], r[22], r[23]);
        *(float4*)(&red[w][24]) = make_float4(r[24], r[25], r[26], r[27]);
    }
    __syncthreads();

    const int g = (w >> 2) * 4;           // first wave of this bt-group
    float rv = 0.f;
    if (lane < 28)
        rv = red[g][lane] + red[g+1][lane] + red[g+2][lane] + red[g+3][lane];

    float rs[28];
    #pragma unroll
    for (int i = 0; i < 28; ++i)
        rs[i] = __int_as_float(__builtin_amdgcn_readlane(__float_as_int(rv), i));

    // ---- Phase 1 softmax over n (wave-uniform scalars) ----
    float e0[N], e1[N];
    float m0 = -1e30f, m1 = -1e30f;
    #pragma unroll
    for (int n = 0; n < N; ++n) {
        const float rinv = rsqrtf(rs[16 + n] * (1.0f/1024.0f) + EPS);
        e0[n] = rs[n]     * rinv * SCALE;  m0 = fmaxf(m0, e0[n]);
        e1[n] = rs[8 + n] * rinv * SCALE;  m1 = fmaxf(m1, e1[n]);
    }
    float es0 = 0.f, es1 = 0.f;
    #pragma unroll
    for (int n = 0; n < N; ++n) {
        e0[n] = __expf(e0[n] - m0);  es0 += e0[n];
        e1[n] = __expf(e1[n] - m1);  es1 += e1[n];
    }

    // ---- Phase 2 merge scalars ----
    const float im0 = rs[26] * rsqrtf(rs[24] * (1.0f/1024.0f) + EPS) * SCALE;
    const float im1 = rs[27] * rsqrtf(rs[25] * (1.0f/1024.0f) + EPS) * SCALE;
    const float mm0 = fmaxf(m0, im0),    mm1 = fmaxf(m1, im1);
    const float wi0 = __expf(m0 - mm0),  wi1 = __expf(m1 - mm1);
    const float wa0 = __expf(im0 - mm0), wa1 = __expf(im1 - mm1);
    const float lse0 = __logf(wi0 * es0 + wa0) + mm0;   // exp(inter_lse-inter_max)==es
    const float lse1 = __logf(wi1 * es1 + wa1) + mm1;
    const float nrm0 = wi0 + wa0,         nrm1 = wi1 + wa1;
    const float cA0 = wi0 / (es0 * nrm0), cA1 = wi1 / (es1 * nrm1);
    const float cp0 = wa0 / nrm0,         cp1 = wa1 / nrm1;

    // ---- Phase E: inter_out from register-resident V; merge; store ----
    float4 A0 = make_float4(0.f,0.f,0.f,0.f);
    float4 A1 = make_float4(0.f,0.f,0.f,0.f);
    #pragma unroll
    for (int n = 0; n < N; ++n) {
        const float4 vv = v[n];
        A0.x += e0[n]*vv.x; A0.y += e0[n]*vv.y; A0.z += e0[n]*vv.z; A0.w += e0[n]*vv.w;
        A1.x += e1[n]*vv.x; A1.y += e1[n]*vv.y; A1.z += e1[n]*vv.z; A1.w += e1[n]*vv.w;
    }
    float4 o0, o1;
    o0.x = cA0*A0.x + cp0*p0.x;  o0.y = cA0*A0.y + cp0*p0.y;
    o0.z = cA0*A0.z + cp0*p0.z;  o0.w = cA0*A0.w + cp0*p0.w;
    o1.x = cA1*A1.x + cp1*p1.x;  o1.y = cA1*A1.y + cp1*p1.y;
    o1.z = cA1*A1.z + cp1*p1.z;  o1.w = cA1*A1.w + cp1*p1.w;
    *(float4*)(out + (size_t)s0 * ROW + btD + d0) = o0;
    *(float4*)(out + (size_t)s1 * ROW + btD + d0) = o1;

    if ((w & 3) == 0 && lane == 0) {      // one writer per (bt, s-pair)
        out[OUT_MM  + (size_t)s0 * BT + bt] = mm0;
        out[OUT_MM  + (size_t)s1 * BT + bt] = mm1;
        out[OUT_LSE + (size_t)s0 * BT + bt] = lse0;
        out[OUT_LSE + (size_t)s1 * BT + bt] = lse1;
    }
}

extern "C" void kernel_launch(void* const* d_in, const int* in_sizes, int n_in,
                              void* d_out, int out_size, void* d_ws, size_t ws_size,
                              hipStream_t stream) {
    const float* q   = (const float*)d_in[0];   // pseudo_queries [8,1024]
    const float* V   = (const float*)d_in[1];   // block_reps     [8,2,2048,1024]
    const float* P   = (const float*)d_in[2];   // partial_sums   [8,2,2048,1024]
    const float* wgt = (const float*)d_in[3];   // norm_weight    [1024]
    float* o = (float*)d_out;

    two_phase_attn_kernel<<<8192, TPB, 0, stream>>>(q, V, P, wgt, o);
}

// Round 12
// 112.517 us; speedup vs baseline: 5.3300x; 1.0978x over previous
//
#include <hip/hip_runtime.h>
#include <math.h>

// (S,N,B,T,D) = (8,8,2,2048,1024)
// Grid 8192 = (xcd 8) x (k 1024); XCD owns contiguous btp range; k%4 = s-pair.
// Block: 512 thr = 8 waves = 2 bt x (n-half h) x (d-half dh).
// Wave handles V rows n0=4h..4h+3 over d-half dh (2 chunks/thread), computes
// dots for BOTH s of its s-pair but P/output only for its own s (s0 if h==0).
// Partials/wave: 14 (vs 28) -> DPP work per element 2x below R7, 4x below R11.
// Phase E: wave computes s0+s1 partials over its 4 rows; partner wave (w^2)
// swaps the other-s partial via LDS. Natural register allocation (no
// launch_bounds: R8/R9/R10 all lost to the allocator).
#define TPB 512

template <int CTRL>
__device__ __forceinline__ float dpp_add(float x) {
    int yi = __builtin_amdgcn_update_dpp(0, __float_as_int(x), CTRL, 0xF, 0xF, true);
    return x + __int_as_float(yi);
}

// 64-lane sum, pure VALU; TOTAL lands in lane 63.
__device__ __forceinline__ float wave_sum63(float x) {
    x = dpp_add<0xB1>(x);    // xor 1
    x = dpp_add<0x4E>(x);    // xor 2
    x = dpp_add<0x141>(x);   // row_half_mirror
    x = dpp_add<0x140>(x);   // row_mirror -> 16-lane row sums
    x = dpp_add<0x142>(x);   // row_bcast15
    x = dpp_add<0x143>(x);   // row_bcast31 -> lane63 = total
    return x;
}

__device__ __forceinline__ float dot4(const float4 a, const float4 b) {
    return a.x*b.x + a.y*b.y + a.z*b.z + a.w*b.w;
}

__global__ void two_phase_attn_kernel(
    const float* __restrict__ q,    // [8][1024]
    const float* __restrict__ V,    // block_reps  [8][2][2048][1024]
    const float* __restrict__ P,    // partial_sums[8][2][2048][1024]
    const float* __restrict__ wgt,  // [1024]
    float* __restrict__ out)        // merged_out | merged_max | merged_lse
{
    constexpr int    N   = 8;
    constexpr int    BT  = 4096;
    constexpr int    D   = 1024;
    constexpr size_t ROW = (size_t)BT * D;
    constexpr size_t OUT_MM  = (size_t)8 * ROW;
    constexpr size_t OUT_LSE = OUT_MM + (size_t)BT * 8;
    constexpr float  SCALE = 0.03125f;
    constexpr float  EPS   = 1e-6f;

    __shared__ float  red[8][16];       // per-wave reduced partials (512 B)
    __shared__ float4 xfer[8][2][64];   // phase-E cross-half partials (16 KB)

    const int tid  = threadIdx.x;
    const int w    = tid >> 6;
    const int lane = tid & 63;

    // XCD-aware decomposition (dispatch round-robins blockIdx % 8 -> XCD)
    const int b   = blockIdx.x;
    const int xcd = b & 7;
    const int k   = b >> 3;
    const int btp = xcd * 256 + (k >> 2);
    const int sp  = k & 3;
    const int s0  = 2 * sp, s1 = s0 + 1;

    const int bt  = 2 * btp + (w >> 2);     // waves 0-3 -> bt_a; 4-7 -> bt_b
    const int h   = (w >> 1) & 1;           // n-half: rows 4h..4h+3
    const int dh  = w & 1;                  // d-half
    const int n0  = 4 * h;
    const int d0  = dh * 512 + lane * 4;    // chunks at d0, d0+256
    const int sown = h ? s1 : s0;
    const size_t btD = (size_t)bt * D;

    // ---- Global loads up front (14 independent float4/thread) ----
    float4 v[4][2];
    #pragma unroll
    for (int i = 0; i < 4; ++i) {
        v[i][0] = *(const float4*)(V + (size_t)(n0 + i) * ROW + btD + d0);
        v[i][1] = *(const float4*)(V + (size_t)(n0 + i) * ROW + btD + d0 + 256);
    }
    float4 p[2];
    p[0] = *(const float4*)(P + (size_t)sown * ROW + btD + d0);
    p[1] = *(const float4*)(P + (size_t)sown * ROW + btD + d0 + 256);

    float4 qw0[2], qw1[2];
    #pragma unroll
    for (int c = 0; c < 2; ++c) {
        const int d = d0 + c * 256;
        const float4 a0 = *(const float4*)(q + s0 * D + d);
        const float4 a1 = *(const float4*)(q + s1 * D + d);
        const float4 wv = *(const float4*)(wgt + d);
        qw0[c] = make_float4(a0.x*wv.x, a0.y*wv.y, a0.z*wv.z, a0.w*wv.w);
        qw1[c] = make_float4(a1.x*wv.x, a1.y*wv.y, a1.z*wv.z, a1.w*wv.w);
    }

    // ---- Per-thread partials: 14 scalars ----
    // r[0..3]=dot(qw0,V[n0+i]) r[4..7]=dot(qw1,V[n0+i]) r[8..11]=vsq[n0+i]
    // r[12]=ssq(P[sown]) r[13]=dot(qw_own,P[sown])
    float r[14];
    #pragma unroll
    for (int i = 0; i < 4; ++i) {
        r[i]     = dot4(qw0[0], v[i][0]) + dot4(qw0[1], v[i][1]);
        r[4 + i] = dot4(qw1[0], v[i][0]) + dot4(qw1[1], v[i][1]);
        r[8 + i] = dot4(v[i][0], v[i][0]) + dot4(v[i][1], v[i][1]);
    }
    r[12] = dot4(p[0], p[0]) + dot4(p[1], p[1]);
    if (h == 0) r[13] = dot4(qw0[0], p[0]) + dot4(qw0[1], p[1]);
    else        r[13] = dot4(qw1[0], p[0]) + dot4(qw1[1], p[1]);

    // ---- Wave reduce (14 independent DPP chains; totals in lane 63) ----
    #pragma unroll
    for (int i = 0; i < 14; ++i) r[i] = wave_sum63(r[i]);

    if (lane == 63) {
        *(float4*)(&red[w][0])  = make_float4(r[0],  r[1],  r[2],  r[3]);
        *(float4*)(&red[w][4])  = make_float4(r[4],  r[5],  r[6],  r[7]);
        *(float4*)(&red[w][8])  = make_float4(r[8],  r[9],  r[10], r[11]);
        *(float4*)(&red[w][12]) = make_float4(r[12], r[13], 0.f,   0.f);
    }
    __syncthreads();

    // ---- Combine totals (uniform-address broadcast reads, all static) ----
    const int g = (w >> 2) * 4;   // waves g..g+3 = (h,dh)=(0,0),(0,1),(1,0),(1,1)
    float e0[N], e1[N], vq[N];
    float ssq0, dp0s, ssq1, dp1s;
    {
        const float4 A = *(const float4*)(&red[g+0][0]),  B = *(const float4*)(&red[g+1][0]);
        e0[0]=A.x+B.x; e0[1]=A.y+B.y; e0[2]=A.z+B.z; e0[3]=A.w+B.w;
        const float4 C = *(const float4*)(&red[g+0][4]),  Dv= *(const float4*)(&red[g+1][4]);
        e1[0]=C.x+Dv.x; e1[1]=C.y+Dv.y; e1[2]=C.z+Dv.z; e1[3]=C.w+Dv.w;
        const float4 E = *(const float4*)(&red[g+0][8]),  F = *(const float4*)(&red[g+1][8]);
        vq[0]=E.x+F.x; vq[1]=E.y+F.y; vq[2]=E.z+F.z; vq[3]=E.w+F.w;
        const float4 G = *(const float4*)(&red[g+0][12]), H = *(const float4*)(&red[g+1][12]);
        ssq0 = G.x+H.x;  dp0s = G.y+H.y;

        const float4 I = *(const float4*)(&red[g+2][0]),  J = *(const float4*)(&red[g+3][0]);
        e0[4]=I.x+J.x; e0[5]=I.y+J.y; e0[6]=I.z+J.z; e0[7]=I.w+J.w;
        const float4 K = *(const float4*)(&red[g+2][4]),  L = *(const float4*)(&red[g+3][4]);
        e1[4]=K.x+L.x; e1[5]=K.y+L.y; e1[6]=K.z+L.z; e1[7]=K.w+L.w;
        const float4 M = *(const float4*)(&red[g+2][8]),  O = *(const float4*)(&red[g+3][8]);
        vq[4]=M.x+O.x; vq[5]=M.y+O.y; vq[6]=M.z+O.z; vq[7]=M.w+O.w;
        const float4 R2= *(const float4*)(&red[g+2][12]), S2= *(const float4*)(&red[g+3][12]);
        ssq1 = R2.x+S2.x; dp1s = R2.y+S2.y;
    }

    // ---- Phase 1 softmax over n (uniform scalars, redundant per thread) ----
    float m0 = -1e30f, m1 = -1e30f;
    #pragma unroll
    for (int n = 0; n < N; ++n) {
        const float rinv = rsqrtf(vq[n] * (1.0f/1024.0f) + EPS);
        e0[n] = e0[n] * rinv * SCALE;  m0 = fmaxf(m0, e0[n]);
        e1[n] = e1[n] * rinv * SCALE;  m1 = fmaxf(m1, e1[n]);
    }
    float es0 = 0.f, es1 = 0.f;
    #pragma unroll
    for (int n = 0; n < N; ++n) {
        e0[n] = __expf(e0[n] - m0);  es0 += e0[n];
        e1[n] = __expf(e1[n] - m1);  es1 += e1[n];
    }

    // ---- Phase 2 merge scalars ----
    const float im0 = dp0s * rsqrtf(ssq0 * (1.0f/1024.0f) + EPS) * SCALE;
    const float im1 = dp1s * rsqrtf(ssq1 * (1.0f/1024.0f) + EPS) * SCALE;
    const float mm0 = fmaxf(m0, im0),    mm1 = fmaxf(m1, im1);
    const float wi0 = __expf(m0 - mm0),  wi1 = __expf(m1 - mm1);
    const float wa0 = __expf(im0 - mm0), wa1 = __expf(im1 - mm1);
    const float lse0 = __logf(wi0 * es0 + wa0) + mm0;   // exp(inter_lse-inter_max)==es
    const float lse1 = __logf(wi1 * es1 + wa1) + mm1;
    const float nrm0 = wi0 + wa0,         nrm1 = wi1 + wa1;
    const float cA0 = wi0 / (es0 * nrm0), cA1 = wi1 / (es1 * nrm1);
    const float cp0 = wa0 / nrm0,         cp1 = wa1 / nrm1;

    // ---- Extract this wave's n-range coefficients (static indices only) ----
    float ce0[4], ce1[4];
    if (h == 0) {
        ce0[0]=e0[0]; ce0[1]=e0[1]; ce0[2]=e0[2]; ce0[3]=e0[3];
        ce1[0]=e1[0]; ce1[1]=e1[1]; ce1[2]=e1[2]; ce1[3]=e1[3];
    } else {
        ce0[0]=e0[4]; ce0[1]=e0[5]; ce0[2]=e0[6]; ce0[3]=e0[7];
        ce1[0]=e1[4]; ce1[1]=e1[5]; ce1[2]=e1[6]; ce1[3]=e1[7];
    }

    // ---- Phase E: partials for BOTH s over this wave's 4 rows ----
    float4 A0[2], A1[2];
    #pragma unroll
    for (int c = 0; c < 2; ++c) {
        A0[c] = make_float4(0.f,0.f,0.f,0.f);
        A1[c] = make_float4(0.f,0.f,0.f,0.f);
    }
    #pragma unroll
    for (int i = 0; i < 4; ++i) {
        #pragma unroll
        for (int c = 0; c < 2; ++c) {
            const float4 vv = v[i][c];
            A0[c].x += ce0[i]*vv.x; A0[c].y += ce0[i]*vv.y;
            A0[c].z += ce0[i]*vv.z; A0[c].w += ce0[i]*vv.w;
            A1[c].x += ce1[i]*vv.x; A1[c].y += ce1[i]*vv.y;
            A1[c].z += ce1[i]*vv.z; A1[c].w += ce1[i]*vv.w;
        }
    }

    // ---- Swap the other-s partial with partner wave (w^2) ----
    if (h == 0) { xfer[w][0][lane] = A1[0]; xfer[w][1][lane] = A1[1]; }
    else        { xfer[w][0][lane] = A0[0]; xfer[w][1][lane] = A0[1]; }
    __syncthreads();

    const int wp = w ^ 2;    // same bt, same dh, other n-half
    const float cAo = h ? cA1 : cA0;
    const float cpo = h ? cp1 : cp0;
    #pragma unroll
    for (int c = 0; c < 2; ++c) {
        const float4 mine = h ? A1[c] : A0[c];
        const float4 oth  = xfer[wp][c][lane];
        float4 o;
        o.x = cAo * (mine.x + oth.x) + cpo * p[c].x;
        o.y = cAo * (mine.y + oth.y) + cpo * p[c].y;
        o.z = cAo * (mine.z + oth.z) + cpo * p[c].z;
        o.w = cAo * (mine.w + oth.w) + cpo * p[c].w;
        *(float4*)(out + (size_t)sown * ROW + btD + d0 + c*256) = o;
    }

    if (dh == 0 && lane == 0) {      // one writer per (bt, s)
        out[OUT_MM  + (size_t)sown * BT + bt] = h ? mm1  : mm0;
        out[OUT_LSE + (size_t)sown * BT + bt] = h ? lse1 : lse0;
    }
}

extern "C" void kernel_launch(void* const* d_in, const int* in_sizes, int n_in,
                              void* d_out, int out_size, void* d_ws, size_t ws_size,
                              hipStream_t stream) {
    const float* q   = (const float*)d_in[0];   // pseudo_queries [8,1024]
    const float* V   = (const float*)d_in[1];   // block_reps     [8,2,2048,1024]
    const float* P   = (const float*)d_in[2];   // partial_sums   [8,2,2048,1024]
    const float* wgt = (const float*)d_in[3];   // norm_weight    [1024]
    float* o = (float*)d_out;

    two_phase_attn_kernel<<<8192, TPB, 0, stream>>>(q, V, P, wgt, o);
}

// Round 13
// 107.675 us; speedup vs baseline: 5.5697x; 1.0450x over previous
//
#include <hip/hip_runtime.h>
#include <math.h>

// (S,N,B,T,D) = (8,8,2,2048,1024)
// One block per bt (4096 blocks, 256 thr = 4 waves). Wave w = s-pair (s0=2w,
// s1=2w+1) AND stages V rows 2w,2w+1 to LDS (vsq folded in). V processed ONCE
// per bt (no per-sp redundancy). All reductions pure-DPP + readlane; only vsq
// crosses waves (32 B). LDS = 32 KB + 32 B -> 4 blocks/CU. Natural VGPR
// (no launch_bounds: R8/R9/R10 allocator lesson).
#define TPB 256

template <int CTRL>
__device__ __forceinline__ float dpp_add(float x) {
    int yi = __builtin_amdgcn_update_dpp(0, __float_as_int(x), CTRL, 0xF, 0xF, true);
    return x + __int_as_float(yi);
}

// 64-lane sum, pure VALU; TOTAL lands in lane 63.
__device__ __forceinline__ float wave_sum63(float x) {
    x = dpp_add<0xB1>(x);    // xor 1
    x = dpp_add<0x4E>(x);    // xor 2
    x = dpp_add<0x141>(x);   // row_half_mirror
    x = dpp_add<0x140>(x);   // row_mirror -> 16-lane row sums
    x = dpp_add<0x142>(x);   // row_bcast15
    x = dpp_add<0x143>(x);   // row_bcast31 -> lane63 = total
    return x;
}

__device__ __forceinline__ float bcast63(float x) {
    return __int_as_float(__builtin_amdgcn_readlane(__float_as_int(x), 63));
}

__device__ __forceinline__ float dot4(const float4 a, const float4 b) {
    return a.x*b.x + a.y*b.y + a.z*b.z + a.w*b.w;
}

__global__ void two_phase_attn_kernel(
    const float* __restrict__ q,    // [8][1024]
    const float* __restrict__ V,    // block_reps  [8][2][2048][1024]
    const float* __restrict__ P,    // partial_sums[8][2][2048][1024]
    const float* __restrict__ wgt,  // [1024]
    float* __restrict__ out)        // merged_out | merged_max | merged_lse
{
    constexpr int    N   = 8;
    constexpr int    BT  = 4096;
    constexpr int    D   = 1024;
    constexpr size_t ROW = (size_t)BT * D;
    constexpr size_t OUT_MM  = (size_t)8 * ROW;
    constexpr size_t OUT_LSE = OUT_MM + (size_t)BT * 8;
    constexpr float  SCALE = 0.03125f;
    constexpr float  EPS   = 1e-6f;

    __shared__ float sV[N][D];      // 32 KB
    __shared__ float sSsq[N];       // 32 B

    const int tid  = threadIdx.x;
    const int w    = tid >> 6;
    const int lane = tid & 63;
    const int s0   = 2 * w, s1 = s0 + 1;   // this wave's s-pair == staged V rows
    const int dl   = lane * 4;
    const int bt   = blockIdx.x;
    const size_t btD = (size_t)bt * D;

    // ---- Independent global loads up front: V rows s0,s1 (8) + P s0,s1 (8) ----
    float4 vs0[4], vs1[4], p0[4], p1[4];
    #pragma unroll
    for (int j = 0; j < 4; ++j) {
        const int d = j * 256 + dl;
        vs0[j] = *(const float4*)(V + (size_t)s0 * ROW + btD + d);
        vs1[j] = *(const float4*)(V + (size_t)s1 * ROW + btD + d);
        p0[j]  = *(const float4*)(P + (size_t)s0 * ROW + btD + d);
        p1[j]  = *(const float4*)(P + (size_t)s1 * ROW + btD + d);
    }

    // ---- qw for this wave's two s rows (q/wgt L2-hot, 36 KB total) ----
    float4 qw0[4], qw1[4];
    #pragma unroll
    for (int j = 0; j < 4; ++j) {
        const int d = j * 256 + dl;
        const float4 a0 = *(const float4*)(q + s0 * D + d);
        const float4 a1 = *(const float4*)(q + s1 * D + d);
        const float4 wv = *(const float4*)(wgt + d);
        qw0[j] = make_float4(a0.x*wv.x, a0.y*wv.y, a0.z*wv.z, a0.w*wv.w);
        qw1[j] = make_float4(a1.x*wv.x, a1.y*wv.y, a1.z*wv.z, a1.w*wv.w);
    }

    // ---- Stage V -> LDS (contiguous b128, conflict-free); vsq from regs ----
    float rv0 = 0.f, rv1 = 0.f;
    #pragma unroll
    for (int j = 0; j < 4; ++j) {
        const int d = j * 256 + dl;
        *(float4*)(&sV[s0][d]) = vs0[j];
        *(float4*)(&sV[s1][d]) = vs1[j];
        rv0 += dot4(vs0[j], vs0[j]);
        rv1 += dot4(vs1[j], vs1[j]);
    }
    rv0 = wave_sum63(rv0);
    rv1 = wave_sum63(rv1);
    if (lane == 63) { sSsq[s0] = rv0; sSsq[s1] = rv1; }

    // ---- P dots (register-resident; independent of the barrier) ----
    float rpa = 0.f, rpb = 0.f, rpc = 0.f, rpd = 0.f;
    #pragma unroll
    for (int j = 0; j < 4; ++j) {
        rpa += dot4(p0[j], p0[j]);
        rpb += dot4(p1[j], p1[j]);
        rpc += dot4(qw0[j], p0[j]);
        rpd += dot4(qw1[j], p1[j]);
    }
    rpa = wave_sum63(rpa);  rpb = wave_sum63(rpb);
    rpc = wave_sum63(rpc);  rpd = wave_sum63(rpd);
    const float ssqP0 = bcast63(rpa), ssqP1 = bcast63(rpb);
    const float dpP0  = bcast63(rpc), dpP1  = bcast63(rpd);

    __syncthreads();    // sV + sSsq published

    // ---- Dots: this wave's 2 s rows vs ALL 8 V rows (LDS, j-outer) ----
    float dt0[N], dt1[N];
    #pragma unroll
    for (int n = 0; n < N; ++n) { dt0[n] = 0.f; dt1[n] = 0.f; }
    #pragma unroll
    for (int j = 0; j < 4; ++j) {
        const int d = j * 256 + dl;
        #pragma unroll
        for (int n = 0; n < N; ++n) {
            const float4 vv = *(const float4*)(&sV[n][d]);
            dt0[n] += dot4(qw0[j], vv);
            dt1[n] += dot4(qw1[j], vv);
        }
    }
    #pragma unroll
    for (int n = 0; n < N; ++n) {
        dt0[n] = bcast63(wave_sum63(dt0[n]));
        dt1[n] = bcast63(wave_sum63(dt1[n]));
    }

    // ---- Phase 1 softmax over n (wave-uniform scalars) ----
    float e0[N], e1[N];
    float m0 = -1e30f, m1 = -1e30f;
    #pragma unroll
    for (int n = 0; n < N; ++n) {
        const float rinv = rsqrtf(sSsq[n] * (1.0f/1024.0f) + EPS);
        e0[n] = dt0[n] * rinv * SCALE;  m0 = fmaxf(m0, e0[n]);
        e1[n] = dt1[n] * rinv * SCALE;  m1 = fmaxf(m1, e1[n]);
    }
    float es0 = 0.f, es1 = 0.f;
    #pragma unroll
    for (int n = 0; n < N; ++n) {
        e0[n] = __expf(e0[n] - m0);  es0 += e0[n];
        e1[n] = __expf(e1[n] - m1);  es1 += e1[n];
    }

    // ---- Phase 2 merge scalars ----
    const float im0 = dpP0 * rsqrtf(ssqP0 * (1.0f/1024.0f) + EPS) * SCALE;
    const float im1 = dpP1 * rsqrtf(ssqP1 * (1.0f/1024.0f) + EPS) * SCALE;
    const float mm0 = fmaxf(m0, im0),    mm1 = fmaxf(m1, im1);
    const float wi0 = __expf(m0 - mm0),  wi1 = __expf(m1 - mm1);
    const float wa0 = __expf(im0 - mm0), wa1 = __expf(im1 - mm1);
    const float lse0 = __logf(wi0 * es0 + wa0) + mm0;   // exp(inter_lse-inter_max)==es
    const float lse1 = __logf(wi1 * es1 + wa1) + mm1;
    const float nrm0 = wi0 + wa0,         nrm1 = wi1 + wa1;
    const float cA0 = wi0 / (es0 * nrm0), cA1 = wi1 / (es1 * nrm1);
    const float cp0 = wa0 / nrm0,         cp1 = wa1 / nrm1;

    // ---- Phase E: inter_out from LDS, merge with P, store ----
    #pragma unroll
    for (int j = 0; j < 4; ++j) {
        const int d = j * 256 + dl;
        float4 A0 = make_float4(0.f,0.f,0.f,0.f);
        float4 A1 = make_float4(0.f,0.f,0.f,0.f);
        #pragma unroll
        for (int n = 0; n < N; ++n) {
            const float4 vv = *(const float4*)(&sV[n][d]);
            A0.x += e0[n]*vv.x; A0.y += e0[n]*vv.y; A0.z += e0[n]*vv.z; A0.w += e0[n]*vv.w;
            A1.x += e1[n]*vv.x; A1.y += e1[n]*vv.y; A1.z += e1[n]*vv.z; A1.w += e1[n]*vv.w;
        }
        float4 o0, o1;
        o0.x = cA0*A0.x + cp0*p0[j].x;  o0.y = cA0*A0.y + cp0*p0[j].y;
        o0.z = cA0*A0.z + cp0*p0[j].z;  o0.w = cA0*A0.w + cp0*p0[j].w;
        o1.x = cA1*A1.x + cp1*p1[j].x;  o1.y = cA1*A1.y + cp1*p1[j].y;
        o1.z = cA1*A1.z + cp1*p1[j].z;  o1.w = cA1*A1.w + cp1*p1[j].w;
        *(float4*)(out + (size_t)s0 * ROW + btD + d) = o0;
        *(float4*)(out + (size_t)s1 * ROW + btD + d) = o1;
    }
    if (lane == 0) {
        out[OUT_MM  + (size_t)s0 * BT + bt] = mm0;
        out[OUT_MM  + (size_t)s1 * BT + bt] = mm1;
        out[OUT_LSE + (size_t)s0 * BT + bt] = lse0;
        out[OUT_LSE + (size_t)s1 * BT + bt] = lse1;
    }
}

extern "C" void kernel_launch(void* const* d_in, const int* in_sizes, int n_in,
                              void* d_out, int out_size, void* d_ws, size_t ws_size,
                              hipStream_t stream) {
    const float* q   = (const float*)d_in[0];   // pseudo_queries [8,1024]
    const float* V   = (const float*)d_in[1];   // block_reps     [8,2,2048,1024]
    const float* P   = (const float*)d_in[2];   // partial_sums   [8,2,2048,1024]
    const float* wgt = (const float*)d_in[3];   // norm_weight    [1024]
    float* o = (float*)d_out;

    two_phase_attn_kernel<<<4096, TPB, 0, stream>>>(q, V, P, wgt, o);
}